// Round 12
// baseline (4769.959 us; speedup 1.0000x reference)
//
#include <hip/hip_runtime.h>

constexpr int kB   = 32;    // batch
constexpr int kNS  = 100;   // n_support
constexpr int kNW  = 10;    // n_way
constexpr int kNZ  = 1000;  // kNS*kNW
constexpr int kD   = 512;   // feature dim
constexpr int kNQ  = 150;   // N*Q query rows
constexpr int kIt  = 15;    // IPM iterations
constexpr int kHalf = 50;
constexpr int kQrt  = 25;   // rows per quarter-strip
constexpr int kPan  = 4;    // pivots per panel (barrier amortization)

// -------------------------------------------------------------------------
// K[b][i][j] = <sup_i, sup_j>  (fp32 accumulate, stored fp64 for the IPM)
__global__ __launch_bounds__(128) void gram_kernel(const float* __restrict__ sup,
                                                   double* __restrict__ K64)
{
    const int i = blockIdx.x;
    const int b = blockIdx.y;
    const int tid = threadIdx.x;
    __shared__ float rowi[kD];
    const float* supb = sup + (size_t)b * kNS * kD;
    reinterpret_cast<float4*>(rowi)[tid] =
        reinterpret_cast<const float4*>(supb + (size_t)i * kD)[tid];
    __syncthreads();
    for (int j = tid; j < kNS; j += 128) {
        const float4* rj = reinterpret_cast<const float4*>(supb + (size_t)j * kD);
        float acc = 0.0f;
        for (int d4 = 0; d4 < kD / 4; ++d4) {
            float4 v = rj[d4];
            acc += rowi[4*d4+0]*v.x + rowi[4*d4+1]*v.y
                 + rowi[4*d4+2]*v.z + rowi[4*d4+3]*v.w;
        }
        K64[((size_t)b * kNS + i) * kNS + j] = (double)acc;
    }
}

// compat[b][i][q] = <sup_i, qry_q>
__global__ __launch_bounds__(256) void compat_kernel(const float* __restrict__ sup,
                                                     const float* __restrict__ qry,
                                                     float* __restrict__ compat)
{
    const int i = blockIdx.x;
    const int b = blockIdx.y;
    const int tid = threadIdx.x;
    __shared__ float rowi[kD];
    const float* supb = sup + (size_t)b * kNS * kD;
    const float* qryb = qry + (size_t)b * kNQ * kD;
    if (tid < 128)
        reinterpret_cast<float4*>(rowi)[tid] =
            reinterpret_cast<const float4*>(supb + (size_t)i * kD)[tid];
    __syncthreads();
    for (int j = tid; j < kNQ; j += 256) {
        const float4* rj = reinterpret_cast<const float4*>(qryb + (size_t)j * kD);
        float acc = 0.0f;
        for (int d4 = 0; d4 < kD / 4; ++d4) {
            float4 v = rj[d4];
            acc += rowi[4*d4+0]*v.x + rowi[4*d4+1]*v.y
                 + rowi[4*d4+2]*v.z + rowi[4*d4+3]*v.w;
        }
        compat[((size_t)b * kNS + i) * kNQ + j] = acc;
    }
}

__global__ __launch_bounds__(256) void init_kernel(double* __restrict__ z,
                                                   double* __restrict__ nu,
                                                   double* __restrict__ s,
                                                   double* __restrict__ lam,
                                                   double* __restrict__ mu_g)
{
    const int b = blockIdx.x;
    const int tid = threadIdx.x;
    for (int m = tid; m < kNZ; m += 256) {
        z[b*kNZ + m]   = 0.0;
        s[b*kNZ + m]   = 1.0;
        lam[b*kNZ + m] = 1.0;
    }
    if (tid < kNS) nu[b*kNS + tid] = 0.0;
    if (tid == 0)  mu_g[b] = 1.0;   // dot(s0,lam0)/kNZ
}

// -------------------------------------------------------------------------
// 4x4 adjugate inverse (one fp64 divide, high ILP).
__device__ __forceinline__ void adj4_inv(const double B[4][4], double I4[4][4])
{
    const double s0 = B[0][0]*B[1][1] - B[1][0]*B[0][1];
    const double s1 = B[0][0]*B[1][2] - B[1][0]*B[0][2];
    const double s2 = B[0][0]*B[1][3] - B[1][0]*B[0][3];
    const double s3 = B[0][1]*B[1][2] - B[1][1]*B[0][2];
    const double s4 = B[0][1]*B[1][3] - B[1][1]*B[0][3];
    const double s5 = B[0][2]*B[1][3] - B[1][2]*B[0][3];
    const double c5 = B[2][2]*B[3][3] - B[3][2]*B[2][3];
    const double c4 = B[2][1]*B[3][3] - B[3][1]*B[2][3];
    const double c3 = B[2][1]*B[3][2] - B[3][1]*B[2][2];
    const double c2 = B[2][0]*B[3][3] - B[3][0]*B[2][3];
    const double c1 = B[2][0]*B[3][2] - B[3][0]*B[2][2];
    const double c0 = B[2][0]*B[3][1] - B[3][0]*B[2][1];
    const double det = s0*c5 - s1*c4 + s2*c3 + s3*c2 - s4*c1 + s5*c0;
    const double id = 1.0 / det;
    I4[0][0] = ( B[1][1]*c5 - B[1][2]*c4 + B[1][3]*c3) * id;
    I4[0][1] = (-B[0][1]*c5 + B[0][2]*c4 - B[0][3]*c3) * id;
    I4[0][2] = ( B[3][1]*s5 - B[3][2]*s4 + B[3][3]*s3) * id;
    I4[0][3] = (-B[2][1]*s5 + B[2][2]*s4 - B[2][3]*s3) * id;
    I4[1][0] = (-B[1][0]*c5 + B[1][2]*c2 - B[1][3]*c1) * id;
    I4[1][1] = ( B[0][0]*c5 - B[0][2]*c2 + B[0][3]*c1) * id;
    I4[1][2] = (-B[3][0]*s5 + B[3][2]*s2 - B[3][3]*s1) * id;
    I4[1][3] = ( B[2][0]*s5 - B[2][2]*s2 + B[2][3]*s1) * id;
    I4[2][0] = ( B[1][0]*c4 - B[1][1]*c2 + B[1][3]*c0) * id;
    I4[2][1] = (-B[0][0]*c4 + B[0][1]*c2 - B[0][3]*c0) * id;
    I4[2][2] = ( B[3][0]*s4 - B[3][1]*s2 + B[3][3]*s0) * id;
    I4[2][3] = (-B[2][0]*s4 + B[2][1]*s2 - B[2][3]*s0) * id;
    I4[3][0] = (-B[1][0]*c3 + B[1][1]*c1 - B[1][2]*c0) * id;
    I4[3][1] = ( B[0][0]*c3 - B[0][1]*c1 + B[0][2]*c0) * id;
    I4[3][2] = (-B[3][0]*s3 + B[3][1]*s1 - B[3][2]*s0) * id;
    I4[3][3] = ( B[2][0]*s3 - B[2][1]*s1 + B[2][2]*s0) * id;
}

// Rank-4 update of 25 owned rows for TWO columns, ONE 25-wide read batch per
// panel row (4 batches/interval instead of 8 -> half the exposed LDS RTTs).
#define PANEL_UPDATE2(H1, H2, WSG, BUF, BASE, SCL1, SCL2, M1, M2)             \
    {                                                                          \
        _Pragma("unroll")                                                      \
        for (int r = 0; r < kQrt; ++r) { H1[r] *= SCL1; H2[r] *= SCL2; }       \
        _Pragma("unroll")                                                      \
        for (int p = 0; p < kPan; ++p) {                                       \
            const double mp1 = M1[p], mp2 = M2[p];                             \
            double w[kQrt];                                                    \
            _Pragma("unroll")                                                  \
            for (int u = 0; u < kQrt; ++u) w[u] = WSG[BUF][p][BASE + u];       \
            __builtin_amdgcn_sched_barrier(0);                                 \
            _Pragma("unroll")                                                  \
            for (int u = 0; u < kQrt; ++u) {                                   \
                H1[u] = fma(-mp1, w[u], H1[u]);                                \
                H2[u] = fma(-mp2, w[u], H2[u]);                                \
            }                                                                  \
        }                                                                      \
    }

// -------------------------------------------------------------------------
// One block (256 thr = 4 waves) per (b,a): h=tid>>6 owns rows [h*25,h*25+25),
// lane=tid&63 owns columns j1=lane and j2=64+lane (j2<100 for lane<36).
// Panel-blocked GJ, 25 barriers. Only the SIGNED panel rows live in LDS:
// B (cols >= k0) reads Wsg directly (sign +); b applies one select/column.
__global__ __launch_bounds__(256) void ipm_invert_kernel(
    const double* __restrict__ K64, const int* __restrict__ labels,
    const double* __restrict__ z, const double* __restrict__ nu,
    const double* __restrict__ s, const double* __restrict__ lam,
    const double* __restrict__ mu_g,
    double* __restrict__ Hinv, double* __restrict__ tvec)
{
    const int b = blockIdx.x / kNW;
    const int a = blockIdx.x - b * kNW;
    const int tid = threadIdx.x;
    const int h = tid >> 6;            // row quarter 0..3
    const int lane = tid & 63;
    const int base = h * kQrt;
    const int j1 = lane;               // always < kNS
    const int j2 = 64 + lane;
    const bool a2 = (j2 < kNS);        // lane < 36
    const int js2 = a2 ? j2 : j1;

    __shared__ double za[kNS], sa[kNS], la[kNS], da[kNS], nus[kNS], r1s[kNS];
    __shared__ double part4[4][kNS];
    __shared__ alignas(16) double Wsg[2][kPan][kNS + 8];  // signed panel rows
    __shared__ int labs[kNS];

    const double* zb = z   + (size_t)b * kNZ;
    const double* sb = s   + (size_t)b * kNZ;
    const double* lb = lam + (size_t)b * kNZ;
    const double* Kb = K64 + (size_t)b * kNS * kNS;

    if (tid < kNS) {
        double zv = zb[tid * kNW + a];
        double sv = sb[tid * kNW + a];
        double lv = lb[tid * kNW + a];
        za[tid] = zv; sa[tid] = sv; la[tid] = lv; da[tid] = lv / sv;
        nus[tid]  = nu[b * kNS + tid];
        labs[tid] = labels[b * kNS + tid];
    }
    __syncthreads();

    // Build both H columns in registers; fused partials of (K z_a).
    double h1[kQrt], h2[kQrt];
    double kz1 = 0.0, kz2 = 0.0;
    #pragma unroll
    for (int r = 0; r < kQrt; ++r) {
        const int i = base + r;
        double kv1 = Kb[(size_t)i * kNS + j1];
        double kv2 = Kb[(size_t)i * kNS + js2];
        kz1 += kv1 * za[i];
        kz2 += kv2 * za[i];
        h1[r] = (i == j1)  ? (kv1 + 1.0 + da[j1])  : kv1;
        h2[r] = (i == js2) ? (kv2 + 1.0 + da[js2]) : kv2;
    }
    part4[h][j1] = kz1;
    if (a2) part4[h][j2] = kz2;
    if (h == 0) {   // seed panel 0 rows (0..3); sign vs k0=0 -> all +
        #pragma unroll
        for (int p = 0; p < kPan; ++p) {
            Wsg[0][p][j1] = h1[p];
            if (a2) Wsg[0][p][j2] = h2[p];
        }
    }
    __syncthreads();
    if (tid < kNS) {
        const double mu = mu_g[b];
        const int i = tid;
        double kz = part4[0][i] + part4[1][i] + part4[2][i] + part4[3][i];
        double yv = (labs[i] == a) ? 1.0 : 0.0;
        double rd = kz + za[i] - yv + la[i] + nus[i];
        double rp = za[i] + sa[i] - 0.1 * yv;      // h = C_REG*y
        double rc = la[i] * sa[i] - 0.1 * mu;      // sigma = 0.1
        r1s[i] = -rd + (rc - la[i] * rp) / sa[i];
    }

    // Panel-blocked Gauss-Jordan inverse: 25 panels, 1 barrier each.
    #pragma unroll 1
    for (int k0 = 0; k0 < kNS; k0 += kPan) {
        const int buf = (k0 >> 2) & 1, nbuf = 1 - buf;
        __syncthreads();                     // Wsg[buf] complete
        // B from signed rows: columns k0+q >= k0 -> stored sign is +
        double B[4][4];
        #pragma unroll
        for (int p = 0; p < 4; ++p)
            #pragma unroll
            for (int q = 0; q < 4; ++q)
                B[p][q] = Wsg[buf][p][k0 + q];
        // b: raw = sig * signed (sig=-1 for processed columns j<k0)
        const bool inp1 = (j1 >= k0) && (j1 < k0 + kPan);
        const bool inp2 = (js2 >= k0) && (js2 < k0 + kPan);
        const double sg1 = (j1  < k0) ? -1.0 : 1.0;
        const double sg2 = (js2 < k0) ? -1.0 : 1.0;
        double b1[4], b2[4];
        #pragma unroll
        for (int p = 0; p < 4; ++p) {
            b1[p] = inp1 ? ((j1  - k0 == p) ? 1.0 : 0.0) : sg1 * Wsg[buf][p][j1];
            b2[p] = inp2 ? ((js2 - k0 == p) ? 1.0 : 0.0) : sg2 * Wsg[buf][p][js2];
        }
        double I4[4][4];
        adj4_inv(B, I4);
        double m1[4], m2[4];
        #pragma unroll
        for (int p = 0; p < 4; ++p) {
            m1[p] = I4[p][0]*b1[0] + I4[p][1]*b1[1] + I4[p][2]*b1[2] + I4[p][3]*b1[3];
            m2[p] = I4[p][0]*b2[0] + I4[p][1]*b2[1] + I4[p][2]*b2[2] + I4[p][3]*b2[3];
        }
        const double scl1 = inp1 ? 0.0 : 1.0;
        const double scl2 = inp2 ? 0.0 : 1.0;
        PANEL_UPDATE2(h1, h2, Wsg, buf, base, scl1, scl2, m1, m2);

        // panel rows get m directly (overwrite generic update)
        if (k0 < base + kQrt && k0 + kPan - 1 >= base) {
            #pragma unroll
            for (int r = 0; r < kQrt; ++r) {
                const int i = base + r;
                if (i >= k0 && i < k0 + kPan) {
                    const int p = i - k0;
                    h1[r] = m1[p];
                    h2[r] = m2[p];
                }
            }
        }
        // write-ahead next panel rows (signed vs kn0)
        const int kn0 = k0 + kPan;
        if (kn0 < kNS && kn0 < base + kQrt && kn0 + kPan - 1 >= base) {
            #pragma unroll
            for (int r = 0; r < kQrt; ++r) {
                const int i = base + r;
                if (i >= kn0 && i < kn0 + kPan) {
                    const int p = i - kn0;
                    Wsg[nbuf][p][j1] = (j1 < kn0) ? -h1[r] : h1[r];
                    if (a2) Wsg[nbuf][p][j2] = (j2 < kn0) ? -h2[r] : h2[r];
                }
            }
        }
    }

    // Write Hinv (coalesced) + t_a = Hinv * r1 (4-way combine via symmetry)
    double* Hb = Hinv + (size_t)(b * kNW + a) * kNS * kNS;
    double tp1 = 0.0, tp2 = 0.0;
    #pragma unroll
    for (int r = 0; r < kQrt; ++r) {
        const int i = base + r;
        Hb[(size_t)i * kNS + j1] = h1[r];
        tp1 += h1[r] * r1s[i];
        if (a2) Hb[(size_t)i * kNS + j2] = h2[r];
        tp2 += h2[r] * r1s[i];
    }
    part4[h][j1] = tp1;
    if (a2) part4[h][j2] = tp2;
    __syncthreads();
    if (tid < kNS)
        tvec[(size_t)(b * kNW + a) * kNS + tid] =
            part4[0][tid] + part4[1][tid] + part4[2][tid] + part4[3][tid];
}

// -------------------------------------------------------------------------
// S[b] = sum_a Hinv_a[b] — 256-block grid-stride (balanced, element-parallel).
__global__ __launch_bounds__(256) void sbuild_kernel(const double* __restrict__ Hinv,
                                                     double* __restrict__ Sg)
{
    const int total = kB * kNS * kNS;
    for (int idx = blockIdx.x * 256 + threadIdx.x; idx < total; idx += 256 * 256) {
        const int b = idx / (kNS * kNS);
        const int e = idx - b * kNS * kNS;
        const double* Hb = Hinv + (size_t)b * kNW * kNS * kNS;
        double acc = 0.0;
        #pragma unroll
        for (int a = 0; a < kNW; ++a) acc += Hb[(size_t)a * kNS * kNS + e];
        Sg[idx] = acc;
    }
}

// -------------------------------------------------------------------------
// One block (256 thr) per b: panel-blocked GJ solve S dnu = sum_a t_a + rp2.
// Same 2-column layout; the rhs is column 100 = lane 36's j2 (never a pivot).
__global__ __launch_bounds__(256) void schur_solve_kernel(
    const double* __restrict__ Sg, const double* __restrict__ tvec,
    const double* __restrict__ z, double* __restrict__ dnu_g)
{
    const int b = blockIdx.x;
    const int tid = threadIdx.x;
    const int h = tid >> 6;
    const int lane = tid & 63;
    const int base = h * kQrt;
    const int j1 = lane;
    const int j2 = 64 + lane;
    const bool a2 = (j2 <= kNS);       // lane <= 36; j2==100 is the rhs column
    const int js2 = a2 ? j2 : j1;

    __shared__ double rhs[kNS];
    __shared__ alignas(16) double Wsg[2][kPan][kNS + 8];

    const double* Sb = Sg   + (size_t)b * kNS * kNS;
    const double* tb = tvec + (size_t)b * kNW * kNS;
    const double* zb = z    + (size_t)b * kNZ;

    if (tid < kNS) {
        double acc = 0.0, rp2 = 0.0;
        #pragma unroll
        for (int a = 0; a < kNW; ++a) {
            acc += tb[a * kNS + tid];
            rp2 += zb[tid * kNW + a];
        }
        rhs[tid] = acc + rp2;
    }
    __syncthreads();

    double h1[kQrt], h2[kQrt];
    #pragma unroll
    for (int r = 0; r < kQrt; ++r) {
        const int i = base + r;
        h1[r] = Sb[(size_t)i * kNS + j1];
        h2[r] = (js2 == kNS) ? rhs[i]
              : Sb[(size_t)i * kNS + ((js2 < kNS) ? js2 : 0)];
    }
    if (h == 0) {
        #pragma unroll
        for (int p = 0; p < kPan; ++p) {
            Wsg[0][p][j1] = h1[p];
            if (a2) Wsg[0][p][j2] = h2[p];
        }
    }

    #pragma unroll 1
    for (int k0 = 0; k0 < kNS; k0 += kPan) {
        const int buf = (k0 >> 2) & 1, nbuf = 1 - buf;
        __syncthreads();
        double B[4][4];
        #pragma unroll
        for (int p = 0; p < 4; ++p)
            #pragma unroll
            for (int q = 0; q < 4; ++q)
                B[p][q] = Wsg[buf][p][k0 + q];
        const bool inp1 = (j1 >= k0) && (j1 < k0 + kPan);
        const bool inp2 = (js2 >= k0) && (js2 < k0 + kPan);   // never for j2==100
        const double sg1 = (j1  < k0) ? -1.0 : 1.0;
        const double sg2 = (js2 < k0) ? -1.0 : 1.0;
        double b1[4], b2[4];
        #pragma unroll
        for (int p = 0; p < 4; ++p) {
            b1[p] = inp1 ? ((j1  - k0 == p) ? 1.0 : 0.0) : sg1 * Wsg[buf][p][j1];
            b2[p] = inp2 ? ((js2 - k0 == p) ? 1.0 : 0.0) : sg2 * Wsg[buf][p][js2];
        }
        double I4[4][4];
        adj4_inv(B, I4);
        double m1[4], m2[4];
        #pragma unroll
        for (int p = 0; p < 4; ++p) {
            m1[p] = I4[p][0]*b1[0] + I4[p][1]*b1[1] + I4[p][2]*b1[2] + I4[p][3]*b1[3];
            m2[p] = I4[p][0]*b2[0] + I4[p][1]*b2[1] + I4[p][2]*b2[2] + I4[p][3]*b2[3];
        }
        const double scl1 = inp1 ? 0.0 : 1.0;
        const double scl2 = inp2 ? 0.0 : 1.0;
        PANEL_UPDATE2(h1, h2, Wsg, buf, base, scl1, scl2, m1, m2);

        if (k0 < base + kQrt && k0 + kPan - 1 >= base) {
            #pragma unroll
            for (int r = 0; r < kQrt; ++r) {
                const int i = base + r;
                if (i >= k0 && i < k0 + kPan) {
                    const int p = i - k0;
                    h1[r] = m1[p];
                    h2[r] = m2[p];
                }
            }
        }
        const int kn0 = k0 + kPan;
        if (kn0 < kNS && kn0 < base + kQrt && kn0 + kPan - 1 >= base) {
            #pragma unroll
            for (int r = 0; r < kQrt; ++r) {
                const int i = base + r;
                if (i >= kn0 && i < kn0 + kPan) {
                    const int p = i - kn0;
                    Wsg[nbuf][p][j1] = (j1 < kn0) ? -h1[r] : h1[r];
                    if (a2) Wsg[nbuf][p][j2] = (j2 < kn0) ? -h2[r] : h2[r];
                }
            }
        }
    }

    if (j2 == kNS) {   // lane 36: rhs column now holds dnu for owned rows
        #pragma unroll
        for (int r = 0; r < kQrt; ++r)
            dnu_g[(size_t)b * kNS + base + r] = h2[r];
    }
}

// -------------------------------------------------------------------------
// 160 blocks x 512 thr (2 classes/block, balanced grid): dz_a = t_a -
// Hinv_a*dnu, ds/dlam, per-class min step-ratio. Barrier counts are uniform
// across both class halves.
__global__ __launch_bounds__(512) void dz_kernel(
    const int* __restrict__ labels,
    const double* __restrict__ Hinv, const double* __restrict__ tvec,
    const double* __restrict__ dnu_g,
    const double* __restrict__ z, const double* __restrict__ s,
    const double* __restrict__ lam, const double* __restrict__ mu_g,
    double* __restrict__ dz_g, double* __restrict__ ds_g,
    double* __restrict__ dl_g, double* __restrict__ minr_g)
{
    const int bid = blockIdx.x;          // [0, 160)
    const int b = bid / 5;
    const int pair = bid - b * 5;
    const int tid = threadIdx.x;
    const int sub = tid >> 8;            // class within pair
    const int a = pair * 2 + sub;
    const int t = tid & 255;
    const int h = t >> 7;
    const int j = t & 127;

    __shared__ double dnus[kNS];
    __shared__ double p2[2][2][kNS];
    __shared__ double red[2][256];

    const double* Hb = Hinv + (size_t)(b * kNW + a) * kNS * kNS;

    if (tid < kNS) dnus[tid] = dnu_g[(size_t)b * kNS + tid];
    __syncthreads();

    if (j < kNS) {
        double p = 0.0;
        #pragma unroll
        for (int r = 0; r < kHalf; ++r)
            p += Hb[(size_t)(h * kHalf + r) * kNS + j] * dnus[h * kHalf + r];
        p2[sub][h][j] = p;
    }
    __syncthreads();

    double lmin = 1e300;
    if (t < kNS) {
        const int i = t;
        const size_t m = (size_t)b * kNZ + i * kNW + a;
        const double mu = mu_g[b];
        double dz = tvec[(size_t)(b * kNW + a) * kNS + i]
                  - (p2[sub][0][i] + p2[sub][1][i]);
        double yv = (labels[b * kNS + i] == a) ? 1.0 : 0.0;
        double zv = z[m], sv = s[m], lv = lam[m];
        double rp = zv + sv - 0.1 * yv;
        double rc = lv * sv - 0.1 * mu;
        double ds = -rp - dz;
        double dl = (-rc - lv * ds) / sv;
        dz_g[m] = dz; ds_g[m] = ds; dl_g[m] = dl;
        if (ds < 0.0) lmin = fmin(lmin, -sv / ds);
        if (dl < 0.0) lmin = fmin(lmin, -lv / dl);
    }
    red[sub][t] = lmin; __syncthreads();
    for (int off = 128; off > 0; off >>= 1) {
        if (t < off) red[sub][t] = fmin(red[sub][t], red[sub][t + off]);
        __syncthreads();
    }
    if (t == 0) minr_g[b * kNW + a] = red[sub][0];
}

// -------------------------------------------------------------------------
// One block per b: alpha from the 10 per-class mins, state update, next mu.
__global__ __launch_bounds__(256) void update_kernel(
    const double* __restrict__ minr_g, const double* __restrict__ dnu_g,
    const double* __restrict__ dz_g, const double* __restrict__ ds_g,
    const double* __restrict__ dl_g,
    double* __restrict__ z, double* __restrict__ nu,
    double* __restrict__ s, double* __restrict__ lam,
    double* __restrict__ mu_g)
{
    const int b = blockIdx.x;
    const int tid = threadIdx.x;
    __shared__ double red[256];

    double am = 1e300;
    #pragma unroll
    for (int a = 0; a < kNW; ++a) am = fmin(am, minr_g[b * kNW + a]);
    const double alpha = fmin(1.0, 0.99 * am);

    double* zb = z   + (size_t)b * kNZ;
    double* sb = s   + (size_t)b * kNZ;
    double* lb = lam + (size_t)b * kNZ;

    double md = 0.0;
    #pragma unroll
    for (int tcl = 0; tcl < 4; ++tcl) {
        const int  e = tid + tcl * 256;
        const size_t m = (size_t)b * kNZ + e;
        if (e < kNZ) {
            double zn = zb[e] + alpha * dz_g[m];
            double sn = sb[e] + alpha * ds_g[m];
            double ln = lb[e] + alpha * dl_g[m];
            zb[e] = zn; sb[e] = sn; lb[e] = ln;
            md += sn * ln;
        }
    }
    red[tid] = md; __syncthreads();
    for (int off = 128; off > 0; off >>= 1) {
        if (tid < off) red[tid] += red[tid + off];
        __syncthreads();
    }
    if (tid == 0) mu_g[b] = red[0] / kNZ;
    if (tid < kNS) nu[(size_t)b * kNS + tid] += alpha * dnu_g[(size_t)b * kNS + tid];
}

// -------------------------------------------------------------------------
// logits[b][q][n] = sum_s compat[b][s][q] * z[b][s*10+n]
__global__ __launch_bounds__(256) void logits_kernel(const float* __restrict__ compat,
                                                     const double* __restrict__ z,
                                                     float* __restrict__ out)
{
    const int b = blockIdx.x;
    const int tid = threadIdx.x;
    const float* cb = compat + (size_t)b * kNS * kNQ;
    const double* zb = z + (size_t)b * kNZ;
    __shared__ double zs[kNZ];
    for (int m = tid; m < kNZ; m += 256) zs[m] = zb[m];
    __syncthreads();
    for (int idx = tid; idx < kNQ * kNW; idx += 256) {
        int q = idx / kNW, n = idx - q * kNW;
        double acc = 0.0;
        for (int s2 = 0; s2 < kNS; ++s2)
            acc += (double)cb[(size_t)s2 * kNQ + q] * zs[s2 * kNW + n];
        out[(size_t)b * kNQ * kNW + idx] = (float)acc;
    }
}

// -------------------------------------------------------------------------
extern "C" void kernel_launch(void* const* d_in, const int* in_sizes, int n_in,
                              void* d_out, int out_size, void* d_ws, size_t ws_size,
                              hipStream_t stream)
{
    const float* sup    = (const float*)d_in[0];   // (32,10,10,512)
    const int*   labels = (const int*)  d_in[1];   // (32,10,10)
    const float* qry    = (const float*)d_in[2];   // (32,10,15,512)
    float* out = (float*)d_out;                    // (32,150,10) fp32

    char* ws = (char*)d_ws;
    size_t off = 0;
    auto alloc = [&](size_t bytes) -> void* {
        void* p = ws + off;
        off += (bytes + 255) & ~(size_t)255;
        return p;
    };
    double* K64    = (double*)alloc(sizeof(double) * kB * kNS * kNS);        // 2.56 MB
    double* z      = (double*)alloc(sizeof(double) * kB * kNZ);
    double* nu     = (double*)alloc(sizeof(double) * kB * kNS);
    double* s      = (double*)alloc(sizeof(double) * kB * kNZ);
    double* lam    = (double*)alloc(sizeof(double) * kB * kNZ);
    double* mu_g   = (double*)alloc(sizeof(double) * kB);
    double* Hinv   = (double*)alloc(sizeof(double) * kB * kNW * kNS * kNS);  // 25.6 MB
    double* Sg     = (double*)alloc(sizeof(double) * kB * kNS * kNS);        // 2.56 MB
    double* tvec   = (double*)alloc(sizeof(double) * kB * kNW * kNS);
    double* dnu_g  = (double*)alloc(sizeof(double) * kB * kNS);
    double* dz_g   = (double*)alloc(sizeof(double) * kB * kNZ);
    double* ds_g   = (double*)alloc(sizeof(double) * kB * kNZ);
    double* dl_g   = (double*)alloc(sizeof(double) * kB * kNZ);
    double* minr_g = (double*)alloc(sizeof(double) * kB * kNW);
    float*  compat = (float*) alloc(sizeof(float)  * kB * kNS * kNQ);        // 1.92 MB

    gram_kernel  <<<dim3(kNS, kB), 128, 0, stream>>>(sup, K64);
    compat_kernel<<<dim3(kNS, kB), 256, 0, stream>>>(sup, qry, compat);
    init_kernel  <<<kB, 256, 0, stream>>>(z, nu, s, lam, mu_g);

    for (int it = 0; it < kIt; ++it) {
        ipm_invert_kernel<<<kB * kNW, 256, 0, stream>>>(K64, labels, z, nu, s,
                                                        lam, mu_g, Hinv, tvec);
        sbuild_kernel<<<256, 256, 0, stream>>>(Hinv, Sg);
        schur_solve_kernel<<<kB, 256, 0, stream>>>(Sg, tvec, z, dnu_g);
        dz_kernel<<<kB * kNW / 2, 512, 0, stream>>>(labels, Hinv, tvec, dnu_g,
                                                    z, s, lam, mu_g,
                                                    dz_g, ds_g, dl_g, minr_g);
        update_kernel<<<kB, 256, 0, stream>>>(minr_g, dnu_g, dz_g, ds_g, dl_g,
                                              z, nu, s, lam, mu_g);
    }

    logits_kernel<<<kB, 256, 0, stream>>>(compat, z, out);
}

// Round 13
// 4668.189 us; speedup vs baseline: 1.0218x; 1.0218x over previous
//
#include <hip/hip_runtime.h>

constexpr int kB   = 32;    // batch
constexpr int kNS  = 100;   // n_support
constexpr int kNW  = 10;    // n_way
constexpr int kNZ  = 1000;  // kNS*kNW
constexpr int kD   = 512;   // feature dim
constexpr int kNQ  = 150;   // N*Q query rows
constexpr int kIt  = 15;    // IPM iterations
constexpr int kHalf = 50;
constexpr int kQrt  = 25;   // rows per quarter-strip
constexpr int kPan  = 4;    // pivots per panel (barrier amortization)

// -------------------------------------------------------------------------
// K[b][i][j] = <sup_i, sup_j>  (fp32 accumulate, stored fp64 for the IPM)
__global__ __launch_bounds__(128) void gram_kernel(const float* __restrict__ sup,
                                                   double* __restrict__ K64)
{
    const int i = blockIdx.x;
    const int b = blockIdx.y;
    const int tid = threadIdx.x;
    __shared__ float rowi[kD];
    const float* supb = sup + (size_t)b * kNS * kD;
    reinterpret_cast<float4*>(rowi)[tid] =
        reinterpret_cast<const float4*>(supb + (size_t)i * kD)[tid];
    __syncthreads();
    for (int j = tid; j < kNS; j += 128) {
        const float4* rj = reinterpret_cast<const float4*>(supb + (size_t)j * kD);
        float acc = 0.0f;
        for (int d4 = 0; d4 < kD / 4; ++d4) {
            float4 v = rj[d4];
            acc += rowi[4*d4+0]*v.x + rowi[4*d4+1]*v.y
                 + rowi[4*d4+2]*v.z + rowi[4*d4+3]*v.w;
        }
        K64[((size_t)b * kNS + i) * kNS + j] = (double)acc;
    }
}

// compat[b][i][q] = <sup_i, qry_q>
__global__ __launch_bounds__(256) void compat_kernel(const float* __restrict__ sup,
                                                     const float* __restrict__ qry,
                                                     float* __restrict__ compat)
{
    const int i = blockIdx.x;
    const int b = blockIdx.y;
    const int tid = threadIdx.x;
    __shared__ float rowi[kD];
    const float* supb = sup + (size_t)b * kNS * kD;
    const float* qryb = qry + (size_t)b * kNQ * kD;
    if (tid < 128)
        reinterpret_cast<float4*>(rowi)[tid] =
            reinterpret_cast<const float4*>(supb + (size_t)i * kD)[tid];
    __syncthreads();
    for (int j = tid; j < kNQ; j += 256) {
        const float4* rj = reinterpret_cast<const float4*>(qryb + (size_t)j * kD);
        float acc = 0.0f;
        for (int d4 = 0; d4 < kD / 4; ++d4) {
            float4 v = rj[d4];
            acc += rowi[4*d4+0]*v.x + rowi[4*d4+1]*v.y
                 + rowi[4*d4+2]*v.z + rowi[4*d4+3]*v.w;
        }
        compat[((size_t)b * kNS + i) * kNQ + j] = acc;
    }
}

__global__ __launch_bounds__(256) void init_kernel(double* __restrict__ z,
                                                   double* __restrict__ nu,
                                                   double* __restrict__ s,
                                                   double* __restrict__ lam,
                                                   double* __restrict__ mu_g)
{
    const int b = blockIdx.x;
    const int tid = threadIdx.x;
    for (int m = tid; m < kNZ; m += 256) {
        z[b*kNZ + m]   = 0.0;
        s[b*kNZ + m]   = 1.0;
        lam[b*kNZ + m] = 1.0;
    }
    if (tid < kNS) nu[b*kNS + tid] = 0.0;
    if (tid == 0)  mu_g[b] = 1.0;   // dot(s0,lam0)/kNZ
}

// -------------------------------------------------------------------------
// 4x4 adjugate inverse (one fp64 divide, high ILP).
__device__ __forceinline__ void adj4_inv(const double B[4][4], double I4[4][4])
{
    const double s0 = B[0][0]*B[1][1] - B[1][0]*B[0][1];
    const double s1 = B[0][0]*B[1][2] - B[1][0]*B[0][2];
    const double s2 = B[0][0]*B[1][3] - B[1][0]*B[0][3];
    const double s3 = B[0][1]*B[1][2] - B[1][1]*B[0][2];
    const double s4 = B[0][1]*B[1][3] - B[1][1]*B[0][3];
    const double s5 = B[0][2]*B[1][3] - B[1][2]*B[0][3];
    const double c5 = B[2][2]*B[3][3] - B[3][2]*B[2][3];
    const double c4 = B[2][1]*B[3][3] - B[3][1]*B[2][3];
    const double c3 = B[2][1]*B[3][2] - B[3][1]*B[2][2];
    const double c2 = B[2][0]*B[3][3] - B[3][0]*B[2][3];
    const double c1 = B[2][0]*B[3][2] - B[3][0]*B[2][2];
    const double c0 = B[2][0]*B[3][1] - B[3][0]*B[2][1];
    const double det = s0*c5 - s1*c4 + s2*c3 + s3*c2 - s4*c1 + s5*c0;
    const double id = 1.0 / det;
    I4[0][0] = ( B[1][1]*c5 - B[1][2]*c4 + B[1][3]*c3) * id;
    I4[0][1] = (-B[0][1]*c5 + B[0][2]*c4 - B[0][3]*c3) * id;
    I4[0][2] = ( B[3][1]*s5 - B[3][2]*s4 + B[3][3]*s3) * id;
    I4[0][3] = (-B[2][1]*s5 + B[2][2]*s4 - B[2][3]*s3) * id;
    I4[1][0] = (-B[1][0]*c5 + B[1][2]*c2 - B[1][3]*c1) * id;
    I4[1][1] = ( B[0][0]*c5 - B[0][2]*c2 + B[0][3]*c1) * id;
    I4[1][2] = (-B[3][0]*s5 + B[3][2]*s2 - B[3][3]*s1) * id;
    I4[1][3] = ( B[2][0]*s5 - B[2][2]*s2 + B[2][3]*s1) * id;
    I4[2][0] = ( B[1][0]*c4 - B[1][1]*c2 + B[1][3]*c0) * id;
    I4[2][1] = (-B[0][0]*c4 + B[0][1]*c2 - B[0][3]*c0) * id;
    I4[2][2] = ( B[3][0]*s4 - B[3][1]*s2 + B[3][3]*s0) * id;
    I4[2][3] = (-B[2][0]*s4 + B[2][1]*s2 - B[2][3]*s0) * id;
    I4[3][0] = (-B[1][0]*c3 + B[1][1]*c1 - B[1][2]*c0) * id;
    I4[3][1] = ( B[0][0]*c3 - B[0][1]*c1 + B[0][2]*c0) * id;
    I4[3][2] = (-B[3][0]*s3 + B[3][1]*s1 - B[3][2]*s0) * id;
    I4[3][3] = ( B[2][0]*s3 - B[2][1]*s1 + B[2][2]*s0) * id;
}

// One signed panel row applied to both owned columns. Reads the row as 13
// double2 (ds_read_b128) starting at the 16B-aligned address base-PAR;
// element base+r sits at window index r+PAR (compile-time field selects).
template<int PAR>
__device__ __forceinline__ void panel_row_fma2(double* __restrict__ H1,
                                               double* __restrict__ H2,
                                               const double* __restrict__ rowp,
                                               double mp1, double mp2)
{
    double2 d[13];
    const double2* wp = (const double2*)(rowp - PAR);
    #pragma unroll
    for (int q = 0; q < 13; ++q) d[q] = wp[q];
    __builtin_amdgcn_sched_barrier(0);   // keep the 13 b128 loads batched
    #pragma unroll
    for (int r = 0; r < kQrt; ++r) {
        const int wi = r + PAR;
        const double wv = (wi & 1) ? d[wi >> 1].y : d[wi >> 1].x;
        H1[r] = fma(-mp1, wv, H1[r]);
        H2[r] = fma(-mp2, wv, H2[r]);
    }
}

// -------------------------------------------------------------------------
// One block (256 thr = 4 waves) per (b,a): h=tid>>6 owns rows [h*25,h*25+25),
// lane=tid&63 owns columns j1=lane and j2=64+lane (j2<100 for lane<36).
// Panel-blocked GJ (25 barriers). All contiguous panel-row reads are b128.
__global__ __launch_bounds__(256) void ipm_invert_kernel(
    const double* __restrict__ K64, const int* __restrict__ labels,
    const double* __restrict__ z, const double* __restrict__ nu,
    const double* __restrict__ s, const double* __restrict__ lam,
    const double* __restrict__ mu_g,
    double* __restrict__ Hinv, double* __restrict__ tvec)
{
    const int b = blockIdx.x / kNW;
    const int a = blockIdx.x - b * kNW;
    const int tid = threadIdx.x;
    const int h = tid >> 6;            // row quarter 0..3
    const int lane = tid & 63;
    const int base = h * kQrt;
    const int j1 = lane;               // always < kNS
    const int j2 = 64 + lane;
    const bool a2 = (j2 < kNS);        // lane < 36
    const int js2 = a2 ? j2 : j1;

    __shared__ double za[kNS], sa[kNS], la[kNS], da[kNS], nus[kNS], r1s[kNS];
    __shared__ double part4[4][kNS];
    __shared__ alignas(16) double Wr [2][kPan][kNS + 8];  // raw panel rows
    __shared__ alignas(16) double Wsg[2][kPan][kNS + 8];  // signed panel rows
    __shared__ int labs[kNS];

    const double* zb = z   + (size_t)b * kNZ;
    const double* sb = s   + (size_t)b * kNZ;
    const double* lb = lam + (size_t)b * kNZ;
    const double* Kb = K64 + (size_t)b * kNS * kNS;

    if (tid < kNS) {
        double zv = zb[tid * kNW + a];
        double sv = sb[tid * kNW + a];
        double lv = lb[tid * kNW + a];
        za[tid] = zv; sa[tid] = sv; la[tid] = lv; da[tid] = lv / sv;
        nus[tid]  = nu[b * kNS + tid];
        labs[tid] = labels[b * kNS + tid];
    }
    __syncthreads();

    // Build both H columns in registers; fused partials of (K z_a).
    double h1[kQrt], h2[kQrt];
    double kz1 = 0.0, kz2 = 0.0;
    #pragma unroll
    for (int r = 0; r < kQrt; ++r) {
        const int i = base + r;
        double kv1 = Kb[(size_t)i * kNS + j1];
        double kv2 = Kb[(size_t)i * kNS + js2];
        kz1 += kv1 * za[i];
        kz2 += kv2 * za[i];
        h1[r] = (i == j1)  ? (kv1 + 1.0 + da[j1])  : kv1;
        h2[r] = (i == js2) ? (kv2 + 1.0 + da[js2]) : kv2;
    }
    part4[h][j1] = kz1;
    if (a2) part4[h][j2] = kz2;
    if (h == 0) {   // seed panel 0 rows (0..3); sign vs k0=0 -> all +
        #pragma unroll
        for (int p = 0; p < kPan; ++p) {
            Wr [0][p][j1] = h1[p];  Wsg[0][p][j1] = h1[p];
            if (a2) { Wr[0][p][j2] = h2[p]; Wsg[0][p][j2] = h2[p]; }
        }
    }
    __syncthreads();
    if (tid < kNS) {
        const double mu = mu_g[b];
        const int i = tid;
        double kz = part4[0][i] + part4[1][i] + part4[2][i] + part4[3][i];
        double yv = (labs[i] == a) ? 1.0 : 0.0;
        double rd = kz + za[i] - yv + la[i] + nus[i];
        double rp = za[i] + sa[i] - 0.1 * yv;      // h = C_REG*y
        double rc = la[i] * sa[i] - 0.1 * mu;      // sigma = 0.1
        r1s[i] = -rd + (rc - la[i] * rp) / sa[i];
    }

    // Panel-blocked Gauss-Jordan inverse: 25 panels, 1 barrier each.
    #pragma unroll 1
    for (int k0 = 0; k0 < kNS; k0 += kPan) {
        const int buf = (k0 >> 2) & 1, nbuf = 1 - buf;
        __syncthreads();                     // Wr/Wsg[buf] complete
        // B = panel rows x panel cols; k0 is 4-aligned -> b128 reads
        double B[4][4];
        #pragma unroll
        for (int p = 0; p < 4; ++p) {
            const double2* bp = (const double2*)(&Wr[buf][p][k0]);
            double2 x0 = bp[0], x1 = bp[1];
            B[p][0] = x0.x; B[p][1] = x0.y; B[p][2] = x1.x; B[p][3] = x1.y;
        }
        // rhs: e_q for panel columns, else raw panel-row entries of col j
        const bool inp1 = (j1 >= k0) && (j1 < k0 + kPan);
        const bool inp2 = (js2 >= k0) && (js2 < k0 + kPan);
        double b1[4], b2[4];
        #pragma unroll
        for (int p = 0; p < 4; ++p) {
            b1[p] = inp1 ? ((j1  - k0 == p) ? 1.0 : 0.0) : Wr[buf][p][j1];
            b2[p] = inp2 ? ((js2 - k0 == p) ? 1.0 : 0.0) : Wr[buf][p][js2];
        }
        double I4[4][4];
        adj4_inv(B, I4);
        double m1[4], m2[4];
        #pragma unroll
        for (int p = 0; p < 4; ++p) {
            m1[p] = I4[p][0]*b1[0] + I4[p][1]*b1[1] + I4[p][2]*b1[2] + I4[p][3]*b1[3];
            m2[p] = I4[p][0]*b2[0] + I4[p][1]*b2[1] + I4[p][2]*b2[2] + I4[p][3]*b2[3];
        }
        const double scl1 = inp1 ? 0.0 : 1.0;
        const double scl2 = inp2 ? 0.0 : 1.0;
        #pragma unroll
        for (int r = 0; r < kQrt; ++r) { h1[r] *= scl1; h2[r] *= scl2; }
        if ((base & 1) == 0) {               // wave-uniform parity branch
            #pragma unroll
            for (int p = 0; p < kPan; ++p)
                panel_row_fma2<0>(h1, h2, &Wsg[buf][p][base], m1[p], m2[p]);
        } else {
            #pragma unroll
            for (int p = 0; p < kPan; ++p)
                panel_row_fma2<1>(h1, h2, &Wsg[buf][p][base], m1[p], m2[p]);
        }

        // panel rows get m directly (overwrite generic update)
        if (k0 < base + kQrt && k0 + kPan - 1 >= base) {
            #pragma unroll
            for (int r = 0; r < kQrt; ++r) {
                const int i = base + r;
                if (i >= k0 && i < k0 + kPan) {
                    const int p = i - k0;
                    h1[r] = m1[p];
                    h2[r] = m2[p];
                }
            }
        }
        // write-ahead next panel rows (raw + signed vs kn0)
        const int kn0 = k0 + kPan;
        if (kn0 < kNS && kn0 < base + kQrt && kn0 + kPan - 1 >= base) {
            #pragma unroll
            for (int r = 0; r < kQrt; ++r) {
                const int i = base + r;
                if (i >= kn0 && i < kn0 + kPan) {
                    const int p = i - kn0;
                    Wr [nbuf][p][j1] = h1[r];
                    Wsg[nbuf][p][j1] = (j1 < kn0) ? -h1[r] : h1[r];
                    if (a2) {
                        Wr [nbuf][p][j2] = h2[r];
                        Wsg[nbuf][p][j2] = (j2 < kn0) ? -h2[r] : h2[r];
                    }
                }
            }
        }
    }

    // Write Hinv (coalesced) + t_a = Hinv * r1 (4-way combine via symmetry)
    double* Hb = Hinv + (size_t)(b * kNW + a) * kNS * kNS;
    double tp1 = 0.0, tp2 = 0.0;
    #pragma unroll
    for (int r = 0; r < kQrt; ++r) {
        const int i = base + r;
        Hb[(size_t)i * kNS + j1] = h1[r];
        tp1 += h1[r] * r1s[i];
        if (a2) Hb[(size_t)i * kNS + j2] = h2[r];
        tp2 += h2[r] * r1s[i];
    }
    part4[h][j1] = tp1;
    if (a2) part4[h][j2] = tp2;
    __syncthreads();
    if (tid < kNS)
        tvec[(size_t)(b * kNW + a) * kNS + tid] =
            part4[0][tid] + part4[1][tid] + part4[2][tid] + part4[3][tid];
}

// -------------------------------------------------------------------------
// S[b] = sum_a Hinv_a[b] — full-GPU streaming reduction (320 blocks).
__global__ __launch_bounds__(256) void sbuild_kernel(const double* __restrict__ Hinv,
                                                     double* __restrict__ Sg)
{
    const int b  = blockIdx.x / kNW;
    const int rc = blockIdx.x - b * kNW;
    const int tid = threadIdx.x;
    const double* Hb = Hinv + (size_t)b * kNW * kNS * kNS;
    for (int e = tid; e < kNS * kNS / kNW; e += 256) {
        const int idx = rc * (kNS * kNS / kNW) + e;
        double acc = 0.0;
        #pragma unroll
        for (int a = 0; a < kNW; ++a) acc += Hb[(size_t)a * kNS * kNS + idx];
        Sg[(size_t)b * kNS * kNS + idx] = acc;
    }
}

// -------------------------------------------------------------------------
// One block (256 thr) per b: panel-blocked GJ solve S dnu = sum_a t_a + rp2.
// Same 2-column layout; the rhs is column 100 = lane 36's j2 (never a pivot).
__global__ __launch_bounds__(256) void schur_solve_kernel(
    const double* __restrict__ Sg, const double* __restrict__ tvec,
    const double* __restrict__ z, double* __restrict__ dnu_g)
{
    const int b = blockIdx.x;
    const int tid = threadIdx.x;
    const int h = tid >> 6;
    const int lane = tid & 63;
    const int base = h * kQrt;
    const int j1 = lane;
    const int j2 = 64 + lane;
    const bool a2 = (j2 <= kNS);       // lane <= 36; j2==100 is the rhs column
    const int js2 = a2 ? j2 : j1;

    __shared__ double rhs[kNS];
    __shared__ alignas(16) double Wr [2][kPan][kNS + 8];
    __shared__ alignas(16) double Wsg[2][kPan][kNS + 8];

    const double* Sb = Sg   + (size_t)b * kNS * kNS;
    const double* tb = tvec + (size_t)b * kNW * kNS;
    const double* zb = z    + (size_t)b * kNZ;

    if (tid < kNS) {
        double acc = 0.0, rp2 = 0.0;
        #pragma unroll
        for (int a = 0; a < kNW; ++a) {
            acc += tb[a * kNS + tid];
            rp2 += zb[tid * kNW + a];
        }
        rhs[tid] = acc + rp2;
    }
    __syncthreads();

    double h1[kQrt], h2[kQrt];
    #pragma unroll
    for (int r = 0; r < kQrt; ++r) {
        const int i = base + r;
        h1[r] = Sb[(size_t)i * kNS + j1];
        h2[r] = (js2 == kNS) ? rhs[i]
              : Sb[(size_t)i * kNS + ((js2 < kNS) ? js2 : 0)];
    }
    if (h == 0) {
        #pragma unroll
        for (int p = 0; p < kPan; ++p) {
            Wr [0][p][j1] = h1[p];  Wsg[0][p][j1] = h1[p];
            if (a2) { Wr[0][p][j2] = h2[p]; Wsg[0][p][j2] = h2[p]; }
        }
    }

    #pragma unroll 1
    for (int k0 = 0; k0 < kNS; k0 += kPan) {
        const int buf = (k0 >> 2) & 1, nbuf = 1 - buf;
        __syncthreads();
        double B[4][4];
        #pragma unroll
        for (int p = 0; p < 4; ++p) {
            const double2* bp = (const double2*)(&Wr[buf][p][k0]);
            double2 x0 = bp[0], x1 = bp[1];
            B[p][0] = x0.x; B[p][1] = x0.y; B[p][2] = x1.x; B[p][3] = x1.y;
        }
        const bool inp1 = (j1 >= k0) && (j1 < k0 + kPan);
        const bool inp2 = (js2 >= k0) && (js2 < k0 + kPan);   // never for j2==100
        double b1[4], b2[4];
        #pragma unroll
        for (int p = 0; p < 4; ++p) {
            b1[p] = inp1 ? ((j1  - k0 == p) ? 1.0 : 0.0) : Wr[buf][p][j1];
            b2[p] = inp2 ? ((js2 - k0 == p) ? 1.0 : 0.0) : Wr[buf][p][js2];
        }
        double I4[4][4];
        adj4_inv(B, I4);
        double m1[4], m2[4];
        #pragma unroll
        for (int p = 0; p < 4; ++p) {
            m1[p] = I4[p][0]*b1[0] + I4[p][1]*b1[1] + I4[p][2]*b1[2] + I4[p][3]*b1[3];
            m2[p] = I4[p][0]*b2[0] + I4[p][1]*b2[1] + I4[p][2]*b2[2] + I4[p][3]*b2[3];
        }
        const double scl1 = inp1 ? 0.0 : 1.0;
        const double scl2 = inp2 ? 0.0 : 1.0;
        #pragma unroll
        for (int r = 0; r < kQrt; ++r) { h1[r] *= scl1; h2[r] *= scl2; }
        if ((base & 1) == 0) {
            #pragma unroll
            for (int p = 0; p < kPan; ++p)
                panel_row_fma2<0>(h1, h2, &Wsg[buf][p][base], m1[p], m2[p]);
        } else {
            #pragma unroll
            for (int p = 0; p < kPan; ++p)
                panel_row_fma2<1>(h1, h2, &Wsg[buf][p][base], m1[p], m2[p]);
        }

        if (k0 < base + kQrt && k0 + kPan - 1 >= base) {
            #pragma unroll
            for (int r = 0; r < kQrt; ++r) {
                const int i = base + r;
                if (i >= k0 && i < k0 + kPan) {
                    const int p = i - k0;
                    h1[r] = m1[p];
                    h2[r] = m2[p];
                }
            }
        }
        const int kn0 = k0 + kPan;
        if (kn0 < kNS && kn0 < base + kQrt && kn0 + kPan - 1 >= base) {
            #pragma unroll
            for (int r = 0; r < kQrt; ++r) {
                const int i = base + r;
                if (i >= kn0 && i < kn0 + kPan) {
                    const int p = i - kn0;
                    Wr [nbuf][p][j1] = h1[r];
                    Wsg[nbuf][p][j1] = (j1 < kn0) ? -h1[r] : h1[r];
                    if (a2) {
                        Wr [nbuf][p][j2] = h2[r];
                        Wsg[nbuf][p][j2] = (j2 < kn0) ? -h2[r] : h2[r];
                    }
                }
            }
        }
    }

    if (j2 == kNS) {   // lane 36: rhs column now holds dnu for owned rows
        #pragma unroll
        for (int r = 0; r < kQrt; ++r)
            dnu_g[(size_t)b * kNS + base + r] = h2[r];
    }
}

// -------------------------------------------------------------------------
// One block per (b,a): dz_a = t_a - Hinv_a*dnu (full-GPU streaming of Hinv),
// ds/dlam, per-block min step-ratio.
__global__ __launch_bounds__(256) void dz_kernel(
    const int* __restrict__ labels,
    const double* __restrict__ Hinv, const double* __restrict__ tvec,
    const double* __restrict__ dnu_g,
    const double* __restrict__ z, const double* __restrict__ s,
    const double* __restrict__ lam, const double* __restrict__ mu_g,
    double* __restrict__ dz_g, double* __restrict__ ds_g,
    double* __restrict__ dl_g, double* __restrict__ minr_g)
{
    const int b = blockIdx.x / kNW;
    const int a = blockIdx.x - b * kNW;
    const int tid = threadIdx.x;
    const int h = tid >> 7;
    const int j = tid & 127;

    __shared__ double dnus[kNS];
    __shared__ double p2[2][kNS];
    __shared__ double red[256];

    const double* Hb = Hinv + (size_t)(b * kNW + a) * kNS * kNS;

    if (tid < kNS) dnus[tid] = dnu_g[(size_t)b * kNS + tid];
    __syncthreads();

    if (j < kNS) {
        double p = 0.0;
        #pragma unroll
        for (int r = 0; r < kHalf; ++r)
            p += Hb[(size_t)(h * kHalf + r) * kNS + j] * dnus[h * kHalf + r];
        p2[h][j] = p;
    }
    __syncthreads();

    double lmin = 1e300;
    if (tid < kNS) {
        const int i = tid;
        const size_t m = (size_t)b * kNZ + i * kNW + a;
        const double mu = mu_g[b];
        double dz = tvec[(size_t)(b * kNW + a) * kNS + i] - (p2[0][i] + p2[1][i]);
        double yv = (labels[b * kNS + i] == a) ? 1.0 : 0.0;
        double zv = z[m], sv = s[m], lv = lam[m];
        double rp = zv + sv - 0.1 * yv;
        double rc = lv * sv - 0.1 * mu;
        double ds = -rp - dz;
        double dl = (-rc - lv * ds) / sv;
        dz_g[m] = dz; ds_g[m] = ds; dl_g[m] = dl;
        if (ds < 0.0) lmin = fmin(lmin, -sv / ds);
        if (dl < 0.0) lmin = fmin(lmin, -lv / dl);
    }
    red[tid] = lmin; __syncthreads();
    for (int off = 128; off > 0; off >>= 1) {
        if (tid < off) red[tid] = fmin(red[tid], red[tid + off]);
        __syncthreads();
    }
    if (tid == 0) minr_g[b * kNW + a] = red[0];
}

// -------------------------------------------------------------------------
// One block per b: alpha from the 10 per-class mins, state update, next mu.
__global__ __launch_bounds__(256) void update_kernel(
    const double* __restrict__ minr_g, const double* __restrict__ dnu_g,
    const double* __restrict__ dz_g, const double* __restrict__ ds_g,
    const double* __restrict__ dl_g,
    double* __restrict__ z, double* __restrict__ nu,
    double* __restrict__ s, double* __restrict__ lam,
    double* __restrict__ mu_g)
{
    const int b = blockIdx.x;
    const int tid = threadIdx.x;
    __shared__ double red[256];

    double am = 1e300;
    #pragma unroll
    for (int a = 0; a < kNW; ++a) am = fmin(am, minr_g[b * kNW + a]);
    const double alpha = fmin(1.0, 0.99 * am);

    double* zb = z   + (size_t)b * kNZ;
    double* sb = s   + (size_t)b * kNZ;
    double* lb = lam + (size_t)b * kNZ;

    double md = 0.0;
    #pragma unroll
    for (int tcl = 0; tcl < 4; ++tcl) {
        const int  e = tid + tcl * 256;
        const size_t m = (size_t)b * kNZ + e;
        if (e < kNZ) {
            double zn = zb[e] + alpha * dz_g[m];
            double sn = sb[e] + alpha * ds_g[m];
            double ln = lb[e] + alpha * dl_g[m];
            zb[e] = zn; sb[e] = sn; lb[e] = ln;
            md += sn * ln;
        }
    }
    red[tid] = md; __syncthreads();
    for (int off = 128; off > 0; off >>= 1) {
        if (tid < off) red[tid] += red[tid + off];
        __syncthreads();
    }
    if (tid == 0) mu_g[b] = red[0] / kNZ;
    if (tid < kNS) nu[(size_t)b * kNS + tid] += alpha * dnu_g[(size_t)b * kNS + tid];
}

// -------------------------------------------------------------------------
// logits[b][q][n] = sum_s compat[b][s][q] * z[b][s*10+n]
__global__ __launch_bounds__(256) void logits_kernel(const float* __restrict__ compat,
                                                     const double* __restrict__ z,
                                                     float* __restrict__ out)
{
    const int b = blockIdx.x;
    const int tid = threadIdx.x;
    const float* cb = compat + (size_t)b * kNS * kNQ;
    const double* zb = z + (size_t)b * kNZ;
    __shared__ double zs[kNZ];
    for (int m = tid; m < kNZ; m += 256) zs[m] = zb[m];
    __syncthreads();
    for (int idx = tid; idx < kNQ * kNW; idx += 256) {
        int q = idx / kNW, n = idx - q * kNW;
        double acc = 0.0;
        for (int s2 = 0; s2 < kNS; ++s2)
            acc += (double)cb[(size_t)s2 * kNQ + q] * zs[s2 * kNW + n];
        out[(size_t)b * kNQ * kNW + idx] = (float)acc;
    }
}

// -------------------------------------------------------------------------
extern "C" void kernel_launch(void* const* d_in, const int* in_sizes, int n_in,
                              void* d_out, int out_size, void* d_ws, size_t ws_size,
                              hipStream_t stream)
{
    const float* sup    = (const float*)d_in[0];   // (32,10,10,512)
    const int*   labels = (const int*)  d_in[1];   // (32,10,10)
    const float* qry    = (const float*)d_in[2];   // (32,10,15,512)
    float* out = (float*)d_out;                    // (32,150,10) fp32

    char* ws = (char*)d_ws;
    size_t off = 0;
    auto alloc = [&](size_t bytes) -> void* {
        void* p = ws + off;
        off += (bytes + 255) & ~(size_t)255;
        return p;
    };
    double* K64    = (double*)alloc(sizeof(double) * kB * kNS * kNS);        // 2.56 MB
    double* z      = (double*)alloc(sizeof(double) * kB * kNZ);
    double* nu     = (double*)alloc(sizeof(double) * kB * kNS);
    double* s      = (double*)alloc(sizeof(double) * kB * kNZ);
    double* lam    = (double*)alloc(sizeof(double) * kB * kNZ);
    double* mu_g   = (double*)alloc(sizeof(double) * kB);
    double* Hinv   = (double*)alloc(sizeof(double) * kB * kNW * kNS * kNS);  // 25.6 MB
    double* Sg     = (double*)alloc(sizeof(double) * kB * kNS * kNS);        // 2.56 MB
    double* tvec   = (double*)alloc(sizeof(double) * kB * kNW * kNS);
    double* dnu_g  = (double*)alloc(sizeof(double) * kB * kNS);
    double* dz_g   = (double*)alloc(sizeof(double) * kB * kNZ);
    double* ds_g   = (double*)alloc(sizeof(double) * kB * kNZ);
    double* dl_g   = (double*)alloc(sizeof(double) * kB * kNZ);
    double* minr_g = (double*)alloc(sizeof(double) * kB * kNW);
    float*  compat = (float*) alloc(sizeof(float)  * kB * kNS * kNQ);        // 1.92 MB

    gram_kernel  <<<dim3(kNS, kB), 128, 0, stream>>>(sup, K64);
    compat_kernel<<<dim3(kNS, kB), 256, 0, stream>>>(sup, qry, compat);
    init_kernel  <<<kB, 256, 0, stream>>>(z, nu, s, lam, mu_g);

    for (int it = 0; it < kIt; ++it) {
        ipm_invert_kernel<<<kB * kNW, 256, 0, stream>>>(K64, labels, z, nu, s,
                                                        lam, mu_g, Hinv, tvec);
        sbuild_kernel<<<kB * kNW, 256, 0, stream>>>(Hinv, Sg);
        schur_solve_kernel<<<kB, 256, 0, stream>>>(Sg, tvec, z, dnu_g);
        dz_kernel<<<kB * kNW, 256, 0, stream>>>(labels, Hinv, tvec, dnu_g,
                                                z, s, lam, mu_g,
                                                dz_g, ds_g, dl_g, minr_g);
        update_kernel<<<kB, 256, 0, stream>>>(minr_g, dnu_g, dz_g, ds_g, dl_g,
                                              z, nu, s, lam, mu_g);
    }

    logits_kernel<<<kB, 256, 0, stream>>>(compat, z, out);
}

// Round 14
// 4539.973 us; speedup vs baseline: 1.0507x; 1.0282x over previous
//
#include <hip/hip_runtime.h>

constexpr int kB   = 32;    // batch
constexpr int kNS  = 100;   // n_support
constexpr int kNW  = 10;    // n_way
constexpr int kNZ  = 1000;  // kNS*kNW
constexpr int kD   = 512;   // feature dim
constexpr int kNQ  = 150;   // N*Q query rows
constexpr int kIt  = 15;    // IPM iterations
constexpr int kHalf = 50;
constexpr int kQrt  = 25;   // rows per quarter-strip
constexpr int kPan  = 4;    // pivots per panel (barrier amortization)

// -------------------------------------------------------------------------
// K[b][i][j] = <sup_i, sup_j>  (fp32 accumulate, stored fp64 for the IPM)
__global__ __launch_bounds__(128) void gram_kernel(const float* __restrict__ sup,
                                                   double* __restrict__ K64)
{
    const int i = blockIdx.x;
    const int b = blockIdx.y;
    const int tid = threadIdx.x;
    __shared__ float rowi[kD];
    const float* supb = sup + (size_t)b * kNS * kD;
    reinterpret_cast<float4*>(rowi)[tid] =
        reinterpret_cast<const float4*>(supb + (size_t)i * kD)[tid];
    __syncthreads();
    for (int j = tid; j < kNS; j += 128) {
        const float4* rj = reinterpret_cast<const float4*>(supb + (size_t)j * kD);
        float acc = 0.0f;
        for (int d4 = 0; d4 < kD / 4; ++d4) {
            float4 v = rj[d4];
            acc += rowi[4*d4+0]*v.x + rowi[4*d4+1]*v.y
                 + rowi[4*d4+2]*v.z + rowi[4*d4+3]*v.w;
        }
        K64[((size_t)b * kNS + i) * kNS + j] = (double)acc;
    }
}

// compat[b][i][q] = <sup_i, qry_q>
__global__ __launch_bounds__(256) void compat_kernel(const float* __restrict__ sup,
                                                     const float* __restrict__ qry,
                                                     float* __restrict__ compat)
{
    const int i = blockIdx.x;
    const int b = blockIdx.y;
    const int tid = threadIdx.x;
    __shared__ float rowi[kD];
    const float* supb = sup + (size_t)b * kNS * kD;
    const float* qryb = qry + (size_t)b * kNQ * kD;
    if (tid < 128)
        reinterpret_cast<float4*>(rowi)[tid] =
            reinterpret_cast<const float4*>(supb + (size_t)i * kD)[tid];
    __syncthreads();
    for (int j = tid; j < kNQ; j += 256) {
        const float4* rj = reinterpret_cast<const float4*>(qryb + (size_t)j * kD);
        float acc = 0.0f;
        for (int d4 = 0; d4 < kD / 4; ++d4) {
            float4 v = rj[d4];
            acc += rowi[4*d4+0]*v.x + rowi[4*d4+1]*v.y
                 + rowi[4*d4+2]*v.z + rowi[4*d4+3]*v.w;
        }
        compat[((size_t)b * kNS + i) * kNQ + j] = acc;
    }
}

__global__ __launch_bounds__(256) void init_kernel(double* __restrict__ z,
                                                   double* __restrict__ nu,
                                                   double* __restrict__ s,
                                                   double* __restrict__ lam,
                                                   double* __restrict__ mu_g)
{
    const int b = blockIdx.x;
    const int tid = threadIdx.x;
    for (int m = tid; m < kNZ; m += 256) {
        z[b*kNZ + m]   = 0.0;
        s[b*kNZ + m]   = 1.0;
        lam[b*kNZ + m] = 1.0;
    }
    if (tid < kNS) nu[b*kNS + tid] = 0.0;
    if (tid == 0)  mu_g[b] = 1.0;   // dot(s0,lam0)/kNZ
}

// -------------------------------------------------------------------------
// 4x4 adjugate inverse (one fp64 divide, high ILP).
__device__ __forceinline__ void adj4_inv(const double B[4][4], double I4[4][4])
{
    const double s0 = B[0][0]*B[1][1] - B[1][0]*B[0][1];
    const double s1 = B[0][0]*B[1][2] - B[1][0]*B[0][2];
    const double s2 = B[0][0]*B[1][3] - B[1][0]*B[0][3];
    const double s3 = B[0][1]*B[1][2] - B[1][1]*B[0][2];
    const double s4 = B[0][1]*B[1][3] - B[1][1]*B[0][3];
    const double s5 = B[0][2]*B[1][3] - B[1][2]*B[0][3];
    const double c5 = B[2][2]*B[3][3] - B[3][2]*B[2][3];
    const double c4 = B[2][1]*B[3][3] - B[3][1]*B[2][3];
    const double c3 = B[2][1]*B[3][2] - B[3][1]*B[2][2];
    const double c2 = B[2][0]*B[3][3] - B[3][0]*B[2][3];
    const double c1 = B[2][0]*B[3][2] - B[3][0]*B[2][2];
    const double c0 = B[2][0]*B[3][1] - B[3][0]*B[2][1];
    const double det = s0*c5 - s1*c4 + s2*c3 + s3*c2 - s4*c1 + s5*c0;
    const double id = 1.0 / det;
    I4[0][0] = ( B[1][1]*c5 - B[1][2]*c4 + B[1][3]*c3) * id;
    I4[0][1] = (-B[0][1]*c5 + B[0][2]*c4 - B[0][3]*c3) * id;
    I4[0][2] = ( B[3][1]*s5 - B[3][2]*s4 + B[3][3]*s3) * id;
    I4[0][3] = (-B[2][1]*s5 + B[2][2]*s4 - B[2][3]*s3) * id;
    I4[1][0] = (-B[1][0]*c5 + B[1][2]*c2 - B[1][3]*c1) * id;
    I4[1][1] = ( B[0][0]*c5 - B[0][2]*c2 + B[0][3]*c1) * id;
    I4[1][2] = (-B[3][0]*s5 + B[3][2]*s2 - B[3][3]*s1) * id;
    I4[1][3] = ( B[2][0]*s5 - B[2][2]*s2 + B[2][3]*s1) * id;
    I4[2][0] = ( B[1][0]*c4 - B[1][1]*c2 + B[1][3]*c0) * id;
    I4[2][1] = (-B[0][0]*c4 + B[0][1]*c2 - B[0][3]*c0) * id;
    I4[2][2] = ( B[3][0]*s4 - B[3][1]*s2 + B[3][3]*s0) * id;
    I4[2][3] = (-B[2][0]*s4 + B[2][1]*s2 - B[2][3]*s0) * id;
    I4[3][0] = (-B[1][0]*c3 + B[1][1]*c1 - B[1][2]*c0) * id;
    I4[3][1] = ( B[0][0]*c3 - B[0][1]*c1 + B[0][2]*c0) * id;
    I4[3][2] = (-B[3][0]*s3 + B[3][1]*s1 - B[3][2]*s0) * id;
    I4[3][3] = ( B[2][0]*s3 - B[2][1]*s1 + B[2][2]*s0) * id;
}

// Rank-4 update of 25 owned rows for TWO columns sharing each broadcast read.
#define PANEL_UPDATE2(H1, H2, WSG, BUF, BASE, SCL1, SCL2, M1, M2)             \
    {                                                                          \
        _Pragma("unroll")                                                      \
        for (int r = 0; r < kQrt; ++r) { H1[r] *= SCL1; H2[r] *= SCL2; }       \
        _Pragma("unroll")                                                      \
        for (int p = 0; p < kPan; ++p) {                                       \
            const double mp1 = M1[p], mp2 = M2[p];                             \
            _Pragma("unroll")                                                  \
            for (int c0 = 0; c0 < 2; ++c0) {                                   \
                const int off0 = c0 ? 13 : 0;                                  \
                const int cnt  = c0 ? 12 : 13;                                 \
                double w[13];                                                  \
                _Pragma("unroll")                                              \
                for (int u = 0; u < 13; ++u)                                   \
                    if (u < cnt) w[u] = WSG[BUF][p][BASE + off0 + u];          \
                __builtin_amdgcn_sched_barrier(0);                             \
                _Pragma("unroll")                                              \
                for (int u = 0; u < 13; ++u)                                   \
                    if (u < cnt) {                                             \
                        H1[off0+u] = fma(-mp1, w[u], H1[off0+u]);              \
                        H2[off0+u] = fma(-mp2, w[u], H2[off0+u]);              \
                    }                                                          \
            }                                                                  \
        }                                                                      \
    }

// -------------------------------------------------------------------------
// One block (256 thr = 4 waves) per (b,a): h=tid>>6 owns rows [h*25,h*25+25),
// lane=tid&63 owns columns j1=lane and j2=64+lane (j2<100 for lane<36).
// Each Wsg broadcast read feeds BOTH columns' FMAs.
__global__ __launch_bounds__(256) void ipm_invert_kernel(
    const double* __restrict__ K64, const int* __restrict__ labels,
    const double* __restrict__ z, const double* __restrict__ nu,
    const double* __restrict__ s, const double* __restrict__ lam,
    const double* __restrict__ mu_g,
    double* __restrict__ Hinv, double* __restrict__ tvec)
{
    const int b = blockIdx.x / kNW;
    const int a = blockIdx.x - b * kNW;
    const int tid = threadIdx.x;
    const int h = tid >> 6;            // row quarter 0..3
    const int lane = tid & 63;
    const int base = h * kQrt;
    const int j1 = lane;               // always < kNS
    const int j2 = 64 + lane;
    const bool a2 = (j2 < kNS);        // lane < 36
    const int js2 = a2 ? j2 : j1;

    __shared__ double za[kNS], sa[kNS], la[kNS], da[kNS], nus[kNS], r1s[kNS];
    __shared__ double part4[4][kNS];
    __shared__ alignas(16) double Wr [2][kPan][kNS + 8];  // raw panel rows
    __shared__ alignas(16) double Wsg[2][kPan][kNS + 8];  // signed panel rows
    __shared__ int labs[kNS];

    const double* zb = z   + (size_t)b * kNZ;
    const double* sb = s   + (size_t)b * kNZ;
    const double* lb = lam + (size_t)b * kNZ;
    const double* Kb = K64 + (size_t)b * kNS * kNS;

    if (tid < kNS) {
        double zv = zb[tid * kNW + a];
        double sv = sb[tid * kNW + a];
        double lv = lb[tid * kNW + a];
        za[tid] = zv; sa[tid] = sv; la[tid] = lv; da[tid] = lv / sv;
        nus[tid]  = nu[b * kNS + tid];
        labs[tid] = labels[b * kNS + tid];
    }
    __syncthreads();

    // Build both H columns in registers; fused partials of (K z_a).
    double h1[kQrt], h2[kQrt];
    double kz1 = 0.0, kz2 = 0.0;
    #pragma unroll
    for (int r = 0; r < kQrt; ++r) {
        const int i = base + r;
        double kv1 = Kb[(size_t)i * kNS + j1];
        double kv2 = Kb[(size_t)i * kNS + js2];
        kz1 += kv1 * za[i];
        kz2 += kv2 * za[i];
        h1[r] = (i == j1)  ? (kv1 + 1.0 + da[j1])  : kv1;
        h2[r] = (i == js2) ? (kv2 + 1.0 + da[js2]) : kv2;
    }
    part4[h][j1] = kz1;
    if (a2) part4[h][j2] = kz2;
    if (h == 0) {   // seed panel 0 rows (0..3); sign vs k0=0 -> all +
        #pragma unroll
        for (int p = 0; p < kPan; ++p) {
            Wr [0][p][j1] = h1[p];  Wsg[0][p][j1] = h1[p];
            if (a2) { Wr[0][p][j2] = h2[p]; Wsg[0][p][j2] = h2[p]; }
        }
    }
    __syncthreads();
    if (tid < kNS) {
        const double mu = mu_g[b];
        const int i = tid;
        double kz = part4[0][i] + part4[1][i] + part4[2][i] + part4[3][i];
        double yv = (labs[i] == a) ? 1.0 : 0.0;
        double rd = kz + za[i] - yv + la[i] + nus[i];
        double rp = za[i] + sa[i] - 0.1 * yv;      // h = C_REG*y
        double rc = la[i] * sa[i] - 0.1 * mu;      // sigma = 0.1
        r1s[i] = -rd + (rc - la[i] * rp) / sa[i];
    }

    // Panel-blocked Gauss-Jordan inverse: 25 panels, 1 barrier each.
    #pragma unroll 1
    for (int k0 = 0; k0 < kNS; k0 += kPan) {
        const int buf = (k0 >> 2) & 1, nbuf = 1 - buf;
        __syncthreads();                     // Wr/Wsg[buf] complete
        // B = panel rows x panel cols (raw, broadcast reads)
        double B[4][4];
        #pragma unroll
        for (int p = 0; p < 4; ++p)
            #pragma unroll
            for (int q = 0; q < 4; ++q)
                B[p][q] = Wr[buf][p][k0 + q];
        // rhs: e_q for panel columns, else panel-row entries of col j
        const bool inp1 = (j1 >= k0) && (j1 < k0 + kPan);
        const bool inp2 = (js2 >= k0) && (js2 < k0 + kPan);
        double b1[4], b2[4];
        #pragma unroll
        for (int p = 0; p < 4; ++p) {
            b1[p] = inp1 ? ((j1  - k0 == p) ? 1.0 : 0.0) : Wr[buf][p][j1];
            b2[p] = inp2 ? ((js2 - k0 == p) ? 1.0 : 0.0) : Wr[buf][p][js2];
        }
        double I4[4][4];
        adj4_inv(B, I4);
        double m1[4], m2[4];
        #pragma unroll
        for (int p = 0; p < 4; ++p) {
            m1[p] = I4[p][0]*b1[0] + I4[p][1]*b1[1] + I4[p][2]*b1[2] + I4[p][3]*b1[3];
            m2[p] = I4[p][0]*b2[0] + I4[p][1]*b2[1] + I4[p][2]*b2[2] + I4[p][3]*b2[3];
        }
        const double scl1 = inp1 ? 0.0 : 1.0;
        const double scl2 = inp2 ? 0.0 : 1.0;
        PANEL_UPDATE2(h1, h2, Wsg, buf, base, scl1, scl2, m1, m2);

        // panel rows get m directly (overwrite generic update)
        if (k0 < base + kQrt && k0 + kPan - 1 >= base) {
            #pragma unroll
            for (int r = 0; r < kQrt; ++r) {
                const int i = base + r;
                if (i >= k0 && i < k0 + kPan) {
                    const int p = i - k0;
                    h1[r] = m1[p];
                    h2[r] = m2[p];
                }
            }
        }
        // write-ahead next panel rows (raw + signed vs kn0)
        const int kn0 = k0 + kPan;
        if (kn0 < kNS && kn0 < base + kQrt && kn0 + kPan - 1 >= base) {
            #pragma unroll
            for (int r = 0; r < kQrt; ++r) {
                const int i = base + r;
                if (i >= kn0 && i < kn0 + kPan) {
                    const int p = i - kn0;
                    Wr [nbuf][p][j1] = h1[r];
                    Wsg[nbuf][p][j1] = (j1 < kn0) ? -h1[r] : h1[r];
                    if (a2) {
                        Wr [nbuf][p][j2] = h2[r];
                        Wsg[nbuf][p][j2] = (j2 < kn0) ? -h2[r] : h2[r];
                    }
                }
            }
        }
    }

    // Write Hinv (coalesced) + t_a = Hinv * r1 (4-way combine via symmetry)
    double* Hb = Hinv + (size_t)(b * kNW + a) * kNS * kNS;
    double tp1 = 0.0, tp2 = 0.0;
    #pragma unroll
    for (int r = 0; r < kQrt; ++r) {
        const int i = base + r;
        Hb[(size_t)i * kNS + j1] = h1[r];
        tp1 += h1[r] * r1s[i];
        if (a2) Hb[(size_t)i * kNS + j2] = h2[r];
        tp2 += h2[r] * r1s[i];
    }
    part4[h][j1] = tp1;
    if (a2) part4[h][j2] = tp2;
    __syncthreads();
    if (tid < kNS)
        tvec[(size_t)(b * kNW + a) * kNS + tid] =
            part4[0][tid] + part4[1][tid] + part4[2][tid] + part4[3][tid];
}

// -------------------------------------------------------------------------
// S[b] = sum_a Hinv_a[b] — full-GPU streaming reduction (320 blocks).
__global__ __launch_bounds__(256) void sbuild_kernel(const double* __restrict__ Hinv,
                                                     double* __restrict__ Sg)
{
    const int b  = blockIdx.x / kNW;
    const int rc = blockIdx.x - b * kNW;
    const int tid = threadIdx.x;
    const double* Hb = Hinv + (size_t)b * kNW * kNS * kNS;
    for (int e = tid; e < kNS * kNS / kNW; e += 256) {
        const int idx = rc * (kNS * kNS / kNW) + e;
        double acc = 0.0;
        #pragma unroll
        for (int a = 0; a < kNW; ++a) acc += Hb[(size_t)a * kNS * kNS + idx];
        Sg[(size_t)b * kNS * kNS + idx] = acc;
    }
}

// -------------------------------------------------------------------------
// One block (256 thr) per b: panel-blocked GJ solve S dnu = sum_a t_a + rp2.
// Same 2-column layout; the rhs is column 100 = lane 36's j2 (never a pivot).
__global__ __launch_bounds__(256) void schur_solve_kernel(
    const double* __restrict__ Sg, const double* __restrict__ tvec,
    const double* __restrict__ z, double* __restrict__ dnu_g)
{
    const int b = blockIdx.x;
    const int tid = threadIdx.x;
    const int h = tid >> 6;
    const int lane = tid & 63;
    const int base = h * kQrt;
    const int j1 = lane;
    const int j2 = 64 + lane;
    const bool a2 = (j2 <= kNS);       // lane <= 36; j2==100 is the rhs column
    const int js2 = a2 ? j2 : j1;

    __shared__ double rhs[kNS];
    __shared__ alignas(16) double Wr [2][kPan][kNS + 8];
    __shared__ alignas(16) double Wsg[2][kPan][kNS + 8];

    const double* Sb = Sg   + (size_t)b * kNS * kNS;
    const double* tb = tvec + (size_t)b * kNW * kNS;
    const double* zb = z    + (size_t)b * kNZ;

    if (tid < kNS) {
        double acc = 0.0, rp2 = 0.0;
        #pragma unroll
        for (int a = 0; a < kNW; ++a) {
            acc += tb[a * kNS + tid];
            rp2 += zb[tid * kNW + a];
        }
        rhs[tid] = acc + rp2;
    }
    __syncthreads();

    double h1[kQrt], h2[kQrt];
    #pragma unroll
    for (int r = 0; r < kQrt; ++r) {
        const int i = base + r;
        h1[r] = Sb[(size_t)i * kNS + j1];
        h2[r] = (js2 == kNS) ? rhs[i]
              : Sb[(size_t)i * kNS + ((js2 < kNS) ? js2 : 0)];
    }
    if (h == 0) {
        #pragma unroll
        for (int p = 0; p < kPan; ++p) {
            Wr [0][p][j1] = h1[p];  Wsg[0][p][j1] = h1[p];
            if (a2) { Wr[0][p][j2] = h2[p]; Wsg[0][p][j2] = h2[p]; }
        }
    }

    #pragma unroll 1
    for (int k0 = 0; k0 < kNS; k0 += kPan) {
        const int buf = (k0 >> 2) & 1, nbuf = 1 - buf;
        __syncthreads();
        double B[4][4];
        #pragma unroll
        for (int p = 0; p < 4; ++p)
            #pragma unroll
            for (int q = 0; q < 4; ++q)
                B[p][q] = Wsg[buf][p][k0 + q];
        const bool inp1 = (j1 >= k0) && (j1 < k0 + kPan);
        const bool inp2 = (js2 >= k0) && (js2 < k0 + kPan);   // never for j2==100
        double b1[4], b2[4];
        #pragma unroll
        for (int p = 0; p < 4; ++p) {
            b1[p] = inp1 ? ((j1  - k0 == p) ? 1.0 : 0.0) : Wr[buf][p][j1];
            b2[p] = inp2 ? ((js2 - k0 == p) ? 1.0 : 0.0) : Wr[buf][p][js2];
        }
        double I4[4][4];
        adj4_inv(B, I4);
        double m1[4], m2[4];
        #pragma unroll
        for (int p = 0; p < 4; ++p) {
            m1[p] = I4[p][0]*b1[0] + I4[p][1]*b1[1] + I4[p][2]*b1[2] + I4[p][3]*b1[3];
            m2[p] = I4[p][0]*b2[0] + I4[p][1]*b2[1] + I4[p][2]*b2[2] + I4[p][3]*b2[3];
        }
        const double scl1 = inp1 ? 0.0 : 1.0;
        const double scl2 = inp2 ? 0.0 : 1.0;
        PANEL_UPDATE2(h1, h2, Wsg, buf, base, scl1, scl2, m1, m2);

        if (k0 < base + kQrt && k0 + kPan - 1 >= base) {
            #pragma unroll
            for (int r = 0; r < kQrt; ++r) {
                const int i = base + r;
                if (i >= k0 && i < k0 + kPan) {
                    const int p = i - k0;
                    h1[r] = m1[p];
                    h2[r] = m2[p];
                }
            }
        }
        const int kn0 = k0 + kPan;
        if (kn0 < kNS && kn0 < base + kQrt && kn0 + kPan - 1 >= base) {
            #pragma unroll
            for (int r = 0; r < kQrt; ++r) {
                const int i = base + r;
                if (i >= kn0 && i < kn0 + kPan) {
                    const int p = i - kn0;
                    Wr [nbuf][p][j1] = h1[r];
                    Wsg[nbuf][p][j1] = (j1 < kn0) ? -h1[r] : h1[r];
                    if (a2) {
                        Wr [nbuf][p][j2] = h2[r];
                        Wsg[nbuf][p][j2] = (j2 < kn0) ? -h2[r] : h2[r];
                    }
                }
            }
        }
    }

    if (j2 == kNS) {   // lane 36: rhs column now holds dnu for owned rows
        #pragma unroll
        for (int r = 0; r < kQrt; ++r)
            dnu_g[(size_t)b * kNS + base + r] = h2[r];
    }
}

// -------------------------------------------------------------------------
// One block per (b,a): dz_a = t_a - Hinv_a*dnu (full-GPU streaming of Hinv),
// ds/dlam, per-block min step-ratio.
__global__ __launch_bounds__(256) void dz_kernel(
    const int* __restrict__ labels,
    const double* __restrict__ Hinv, const double* __restrict__ tvec,
    const double* __restrict__ dnu_g,
    const double* __restrict__ z, const double* __restrict__ s,
    const double* __restrict__ lam, const double* __restrict__ mu_g,
    double* __restrict__ dz_g, double* __restrict__ ds_g,
    double* __restrict__ dl_g, double* __restrict__ minr_g)
{
    const int b = blockIdx.x / kNW;
    const int a = blockIdx.x - b * kNW;
    const int tid = threadIdx.x;
    const int h = tid >> 7;
    const int j = tid & 127;

    __shared__ double dnus[kNS];
    __shared__ double p2[2][kNS];
    __shared__ double red[256];

    const double* Hb = Hinv + (size_t)(b * kNW + a) * kNS * kNS;

    if (tid < kNS) dnus[tid] = dnu_g[(size_t)b * kNS + tid];
    __syncthreads();

    if (j < kNS) {
        double p = 0.0;
        #pragma unroll
        for (int r = 0; r < kHalf; ++r)
            p += Hb[(size_t)(h * kHalf + r) * kNS + j] * dnus[h * kHalf + r];
        p2[h][j] = p;
    }
    __syncthreads();

    double lmin = 1e300;
    if (tid < kNS) {
        const int i = tid;
        const size_t m = (size_t)b * kNZ + i * kNW + a;
        const double mu = mu_g[b];
        double dz = tvec[(size_t)(b * kNW + a) * kNS + i] - (p2[0][i] + p2[1][i]);
        double yv = (labels[b * kNS + i] == a) ? 1.0 : 0.0;
        double zv = z[m], sv = s[m], lv = lam[m];
        double rp = zv + sv - 0.1 * yv;
        double rc = lv * sv - 0.1 * mu;
        double ds = -rp - dz;
        double dl = (-rc - lv * ds) / sv;
        dz_g[m] = dz; ds_g[m] = ds; dl_g[m] = dl;
        if (ds < 0.0) lmin = fmin(lmin, -sv / ds);
        if (dl < 0.0) lmin = fmin(lmin, -lv / dl);
    }
    red[tid] = lmin; __syncthreads();
    for (int off = 128; off > 0; off >>= 1) {
        if (tid < off) red[tid] = fmin(red[tid], red[tid + off]);
        __syncthreads();
    }
    if (tid == 0) minr_g[b * kNW + a] = red[0];
}

// -------------------------------------------------------------------------
// One block per b: alpha from the 10 per-class mins, state update, next mu.
__global__ __launch_bounds__(256) void update_kernel(
    const double* __restrict__ minr_g, const double* __restrict__ dnu_g,
    const double* __restrict__ dz_g, const double* __restrict__ ds_g,
    const double* __restrict__ dl_g,
    double* __restrict__ z, double* __restrict__ nu,
    double* __restrict__ s, double* __restrict__ lam,
    double* __restrict__ mu_g)
{
    const int b = blockIdx.x;
    const int tid = threadIdx.x;
    __shared__ double red[256];

    double am = 1e300;
    #pragma unroll
    for (int a = 0; a < kNW; ++a) am = fmin(am, minr_g[b * kNW + a]);
    const double alpha = fmin(1.0, 0.99 * am);

    double* zb = z   + (size_t)b * kNZ;
    double* sb = s   + (size_t)b * kNZ;
    double* lb = lam + (size_t)b * kNZ;

    double md = 0.0;
    #pragma unroll
    for (int tcl = 0; tcl < 4; ++tcl) {
        const int  e = tid + tcl * 256;
        const size_t m = (size_t)b * kNZ + e;
        if (e < kNZ) {
            double zn = zb[e] + alpha * dz_g[m];
            double sn = sb[e] + alpha * ds_g[m];
            double ln = lb[e] + alpha * dl_g[m];
            zb[e] = zn; sb[e] = sn; lb[e] = ln;
            md += sn * ln;
        }
    }
    red[tid] = md; __syncthreads();
    for (int off = 128; off > 0; off >>= 1) {
        if (tid < off) red[tid] += red[tid + off];
        __syncthreads();
    }
    if (tid == 0) mu_g[b] = red[0] / kNZ;
    if (tid < kNS) nu[(size_t)b * kNS + tid] += alpha * dnu_g[(size_t)b * kNS + tid];
}

// -------------------------------------------------------------------------
// logits[b][q][n] = sum_s compat[b][s][q] * z[b][s*10+n]
__global__ __launch_bounds__(256) void logits_kernel(const float* __restrict__ compat,
                                                     const double* __restrict__ z,
                                                     float* __restrict__ out)
{
    const int b = blockIdx.x;
    const int tid = threadIdx.x;
    const float* cb = compat + (size_t)b * kNS * kNQ;
    const double* zb = z + (size_t)b * kNZ;
    __shared__ double zs[kNZ];
    for (int m = tid; m < kNZ; m += 256) zs[m] = zb[m];
    __syncthreads();
    for (int idx = tid; idx < kNQ * kNW; idx += 256) {
        int q = idx / kNW, n = idx - q * kNW;
        double acc = 0.0;
        for (int s2 = 0; s2 < kNS; ++s2)
            acc += (double)cb[(size_t)s2 * kNQ + q] * zs[s2 * kNW + n];
        out[(size_t)b * kNQ * kNW + idx] = (float)acc;
    }
}

// -------------------------------------------------------------------------
extern "C" void kernel_launch(void* const* d_in, const int* in_sizes, int n_in,
                              void* d_out, int out_size, void* d_ws, size_t ws_size,
                              hipStream_t stream)
{
    const float* sup    = (const float*)d_in[0];   // (32,10,10,512)
    const int*   labels = (const int*)  d_in[1];   // (32,10,10)
    const float* qry    = (const float*)d_in[2];   // (32,10,15,512)
    float* out = (float*)d_out;                    // (32,150,10) fp32

    char* ws = (char*)d_ws;
    size_t off = 0;
    auto alloc = [&](size_t bytes) -> void* {
        void* p = ws + off;
        off += (bytes + 255) & ~(size_t)255;
        return p;
    };
    double* K64    = (double*)alloc(sizeof(double) * kB * kNS * kNS);        // 2.56 MB
    double* z      = (double*)alloc(sizeof(double) * kB * kNZ);
    double* nu     = (double*)alloc(sizeof(double) * kB * kNS);
    double* s      = (double*)alloc(sizeof(double) * kB * kNZ);
    double* lam    = (double*)alloc(sizeof(double) * kB * kNZ);
    double* mu_g   = (double*)alloc(sizeof(double) * kB);
    double* Hinv   = (double*)alloc(sizeof(double) * kB * kNW * kNS * kNS);  // 25.6 MB
    double* Sg     = (double*)alloc(sizeof(double) * kB * kNS * kNS);        // 2.56 MB
    double* tvec   = (double*)alloc(sizeof(double) * kB * kNW * kNS);
    double* dnu_g  = (double*)alloc(sizeof(double) * kB * kNS);
    double* dz_g   = (double*)alloc(sizeof(double) * kB * kNZ);
    double* ds_g   = (double*)alloc(sizeof(double) * kB * kNZ);
    double* dl_g   = (double*)alloc(sizeof(double) * kB * kNZ);
    double* minr_g = (double*)alloc(sizeof(double) * kB * kNW);
    float*  compat = (float*) alloc(sizeof(float)  * kB * kNS * kNQ);        // 1.92 MB

    gram_kernel  <<<dim3(kNS, kB), 128, 0, stream>>>(sup, K64);
    compat_kernel<<<dim3(kNS, kB), 256, 0, stream>>>(sup, qry, compat);
    init_kernel  <<<kB, 256, 0, stream>>>(z, nu, s, lam, mu_g);

    for (int it = 0; it < kIt; ++it) {
        ipm_invert_kernel<<<kB * kNW, 256, 0, stream>>>(K64, labels, z, nu, s,
                                                        lam, mu_g, Hinv, tvec);
        sbuild_kernel<<<kB * kNW, 256, 0, stream>>>(Hinv, Sg);
        schur_solve_kernel<<<kB, 256, 0, stream>>>(Sg, tvec, z, dnu_g);
        dz_kernel<<<kB * kNW, 256, 0, stream>>>(labels, Hinv, tvec, dnu_g,
                                                z, s, lam, mu_g,
                                                dz_g, ds_g, dl_g, minr_g);
        update_kernel<<<kB, 256, 0, stream>>>(minr_g, dnu_g, dz_g, ds_g, dl_g,
                                              z, nu, s, lam, mu_g);
    }

    logits_kernel<<<kB, 256, 0, stream>>>(compat, z, out);
}